// Round 4
// baseline (1574.901 us; speedup 1.0000x reference)
//
#include <hip/hip_runtime.h>
#include <math.h>

#define NN    100000
#define INF_  256
#define HID   128
#define OUTF  16
#define NE    1600000
#define BUK   64
#define NBUK  ((NN + BUK - 1) / BUK)   // 1563
#define SCAN_VPT 7                     // 256*7 = 1792 >= NBUK

typedef __attribute__((ext_vector_type(4))) float f32x4;
typedef __attribute__((ext_vector_type(8))) short bf16x8;

__device__ inline unsigned short f32_to_bf16(float f) {
  union { float f; unsigned int u; } v; v.f = f;
  unsigned int x = v.u;
  unsigned int r = x + 0x7fffu + ((x >> 16) & 1u);  // RNE
  return (unsigned short)(r >> 16);
}
__device__ inline float bf16lo_to_f32(unsigned int u) {
  union { unsigned int u; float f; } v; v.u = u << 16; return v.f;
}
__device__ inline float bf16hi_to_f32(unsigned int u) {
  union { unsigned int u; float f; } v; v.u = u & 0xffff0000u; return v.f;
}

// ---------------------------------------------------------------- degree
__global__ __launch_bounds__(256) void k_deg(const int* __restrict__ dst,
                                             int* __restrict__ deg) {
  int i = blockIdx.x * blockDim.x + threadIdx.x;
  const int stride = gridDim.x * blockDim.x;
  for (; i < NE; i += stride) atomicAdd(&deg[dst[i]], 1);
}

// ---------------------------------------------------------------- dinv = rsqrt(deg+1)
__global__ __launch_bounds__(256) void k_dinv(const int* __restrict__ deg,
                                              float* __restrict__ dinv) {
  int i = blockIdx.x * blockDim.x + threadIdx.x;
  if (i < NN) dinv[i] = rsqrtf((float)(deg[i] + 1));
}

// ---------------------------------------------------------------- W prep (bf16, transposed, pre-swizzled 16B chunks)
__global__ __launch_bounds__(256) void k_wprep(const float* __restrict__ W,
                                               unsigned short* __restrict__ WTs) {
  const int i = blockIdx.x * 256 + threadIdx.x;
  if (i >= INF_ * HID) return;
  const int k = i >> 7, n = i & 127;
  const int s = k >> 5, c = (k >> 3) & 3, j = k & 7;
  const int chunk = s * 512 + n * 4 + (c ^ (n & 3));
  WTs[chunk * 8 + j] = f32_to_bf16(W[i]);
}

// ---------------------------------------------------------------- MFMA GEMM: h2b = bf16( (x @ Wc) * dinv[row] )
__global__ __launch_bounds__(256) void k_gemm(const float* __restrict__ x,
                                              const unsigned short* __restrict__ WTs,
                                              const float* __restrict__ dinv,
                                              unsigned short* __restrict__ h2b) {
  __shared__ unsigned short xs[128 * 32];
  __shared__ unsigned short ws[128 * 32];
  const int tid = threadIdx.x;
  const int wave = tid >> 6, lane = tid & 63;
  const int l15 = lane & 15, l4 = lane >> 4;
  const int row0 = blockIdx.x * 128;

  f32x4 acc[2][8];
#pragma unroll
  for (int rb = 0; rb < 2; ++rb)
#pragma unroll
    for (int n = 0; n < 8; ++n) { acc[rb][n].x = 0.f; acc[rb][n].y = 0.f; acc[rb][n].z = 0.f; acc[rb][n].w = 0.f; }

  for (int s = 0; s < 8; ++s) {
#pragma unroll
    for (int p = 0; p < 2; ++p) {
      const int c = tid + p * 256;
      const int row = c >> 2, kc = c & 3;
      const int grow = row0 + row;
      unsigned short tmp[8];
      if (grow < NN) {
        const float4 v0 = *(const float4*)&x[(size_t)grow * INF_ + s * 32 + kc * 8];
        const float4 v1 = *(const float4*)&x[(size_t)grow * INF_ + s * 32 + kc * 8 + 4];
        tmp[0] = f32_to_bf16(v0.x); tmp[1] = f32_to_bf16(v0.y);
        tmp[2] = f32_to_bf16(v0.z); tmp[3] = f32_to_bf16(v0.w);
        tmp[4] = f32_to_bf16(v1.x); tmp[5] = f32_to_bf16(v1.y);
        tmp[6] = f32_to_bf16(v1.z); tmp[7] = f32_to_bf16(v1.w);
      } else {
#pragma unroll
        for (int j = 0; j < 8; ++j) tmp[j] = 0;
      }
      const int phys = kc ^ (row & 3);
      *(bf16x8*)&xs[(row * 4 + phys) * 8] = *(bf16x8*)tmp;
    }
#pragma unroll
    for (int p = 0; p < 2; ++p) {
      const int c = tid + p * 256;
      *(bf16x8*)&ws[c * 8] = *(const bf16x8*)&WTs[(s * 512 + c) * 8];
    }
    __syncthreads();
    bf16x8 af[2];
#pragma unroll
    for (int rb = 0; rb < 2; ++rb) {
      const int row = wave * 32 + rb * 16 + l15;
      af[rb] = *(const bf16x8*)&xs[(row * 4 + (l4 ^ (row & 3))) * 8];
    }
#pragma unroll
    for (int n = 0; n < 8; ++n) {
      const int col = n * 16 + l15;
      const bf16x8 bf = *(const bf16x8*)&ws[(col * 4 + (l4 ^ (col & 3))) * 8];
      acc[0][n] = __builtin_amdgcn_mfma_f32_16x16x32_bf16(af[0], bf, acc[0][n], 0, 0, 0);
      acc[1][n] = __builtin_amdgcn_mfma_f32_16x16x32_bf16(af[1], bf, acc[1][n], 0, 0, 0);
    }
    __syncthreads();
  }
#pragma unroll
  for (int rb = 0; rb < 2; ++rb) {
#pragma unroll
    for (int r = 0; r < 4; ++r) {
      const int rowg = row0 + wave * 32 + rb * 16 + l4 * 4 + r;
      if (rowg < NN) {
        const float dv = dinv[rowg];
#pragma unroll
        for (int n = 0; n < 8; ++n)
          h2b[(size_t)rowg * HID + n * 16 + l15] = f32_to_bf16(acc[rb][n][r] * dv);
      }
    }
  }
}

// ---------------------------------------------------------------- bucket counts from deg (no atomics)
__global__ __launch_bounds__(64) void k_bucketsum(const int* __restrict__ deg,
                                                  int* __restrict__ bcnt) {
  const int b = blockIdx.x, t = threadIdx.x;
  const int idx = b * BUK + t;
  int v = (idx < NN) ? deg[idx] : 0;
#pragma unroll
  for (int off = 32; off; off >>= 1) v += __shfl_down(v, off);
  if (t == 0) bcnt[b] = v;
}

// ---------------------------------------------------------------- single-block exclusive scan of NBUK counts
__global__ __launch_bounds__(256) void k_bscan(const int* __restrict__ bcnt,
                                               int* __restrict__ boff,
                                               int* __restrict__ cur) {
  __shared__ int sh[256];
  const int t = threadIdx.x;
  int v[SCAN_VPT];
  int s = 0;
#pragma unroll
  for (int j = 0; j < SCAN_VPT; ++j) {
    const int idx = t * SCAN_VPT + j;
    v[j] = (idx < NBUK) ? bcnt[idx] : 0;
    s += v[j];
  }
  sh[t] = s;
  __syncthreads();
  for (int off = 1; off < 256; off <<= 1) {
    int tmp = (t >= off) ? sh[t - off] : 0;
    __syncthreads();
    sh[t] += tmp;
    __syncthreads();
  }
  int run = (t > 0) ? sh[t - 1] : 0;
#pragma unroll
  for (int j = 0; j < SCAN_VPT; ++j) {
    const int idx = t * SCAN_VPT + j;
    if (idx < NBUK) { boff[idx] = run; cur[idx] = run; }
    run += v[j];
  }
  if (t == 255) boff[NBUK] = run;
}

// ---------------------------------------------------------------- bin fill: packed word = src*64 | (dst&63)
__global__ __launch_bounds__(256) void k_binfill(const int* __restrict__ src,
                                                 const int* __restrict__ dst,
                                                 int* __restrict__ cur,
                                                 unsigned int* __restrict__ binned) {
  int i = blockIdx.x * blockDim.x + threadIdx.x;
  const int stride = gridDim.x * blockDim.x;
  for (; i < NE; i += stride) {
    const int d = dst[i];
    const int pos = atomicAdd(&cur[d >> 6], 1);
    binned[pos] = ((unsigned)src[i] << 6) | (unsigned)(d & 63);
  }
}

// ---------------------------------------------------------------- per-bucket LDS accumulate + fused finalize
// block = 1 bucket (64 nodes), 256 thr (4 waves). agg layout: [node][half*64 + lane]
__global__ __launch_bounds__(256) void k_aggfin(const unsigned int* __restrict__ binned,
                                                const int* __restrict__ boff,
                                                const unsigned short* __restrict__ h2b,
                                                const float* __restrict__ dinv,
                                                const float* __restrict__ bc,
                                                const float* __restrict__ Wl,
                                                const float* __restrict__ bl,
                                                float* __restrict__ out) {
  __shared__ float aggf[BUK * HID];  // 32 KB
  const int tid = threadIdx.x;
  const int wid = tid >> 6, lane = tid & 63;
  const int b = blockIdx.x;

  // zero agg
#pragma unroll
  for (int j = 0; j < 8; ++j)
    ((float4*)aggf)[j * 256 + tid] = make_float4(0.f, 0.f, 0.f, 0.f);
  __syncthreads();

  const int e0 = boff[b], e1 = boff[b + 1];
  const unsigned* h2u = (const unsigned*)h2b;  // dword view: row v at h2u + v*64, lane's dword at +lane

  // edge-parallel accumulate: wave processes 64-edge chunks (chunk c -> wave c&3)
  for (int s = e0 + wid * 64; s < e1; s += 256) {
    const int idx = s + lane;
    const unsigned wv = binned[(idx < e1) ? idx : (e1 - 1)];
    const int n = min(64, e1 - s);
    if (n == 64) {
#pragma unroll 8
      for (int j = 0; j < 64; ++j) {
        const unsigned w = __builtin_amdgcn_readlane(wv, j);
        const unsigned u = h2u[((size_t)(w >> 6) << 6) + lane];
        const int vloc = (int)(w & 63u) << 7;
        atomicAdd(&aggf[vloc + lane], bf16lo_to_f32(u));
        atomicAdd(&aggf[vloc + 64 + lane], bf16hi_to_f32(u));
      }
    } else {
      for (int j = 0; j < n; ++j) {
        const unsigned w = __builtin_amdgcn_readlane(wv, j);
        const unsigned u = h2u[((size_t)(w >> 6) << 6) + lane];
        const int vloc = (int)(w & 63u) << 7;
        atomicAdd(&aggf[vloc + lane], bf16lo_to_f32(u));
        atomicAdd(&aggf[vloc + 64 + lane], bf16hi_to_f32(u));
      }
    }
  }
  __syncthreads();

  // finalize: wave w handles nodes w*16 .. w*16+15
  const int c0 = lane * 2;
  // hoist Wl rows c0, c0+1 into registers (32 floats)
  float wa[OUTF], wb[OUTF];
  {
    const float4* pa = (const float4*)&Wl[(size_t)c0 * OUTF];
    const float4* pb = (const float4*)&Wl[(size_t)(c0 + 1) * OUTF];
#pragma unroll
    for (int q = 0; q < 4; ++q) {
      const float4 a = pa[q], bq = pb[q];
      wa[q * 4 + 0] = a.x;  wa[q * 4 + 1] = a.y;  wa[q * 4 + 2] = a.z;  wa[q * 4 + 3] = a.w;
      wb[q * 4 + 0] = bq.x; wb[q * 4 + 1] = bq.y; wb[q * 4 + 2] = bq.z; wb[q * 4 + 3] = bq.w;
    }
  }
  const float2 bcv = *(const float2*)&bc[c0];
  const float blv = bl[(lane >> 2) & 15];

  for (int r = 0; r < 16; ++r) {
    const int vloc = wid * 16 + r;
    const int vg = b * BUK + vloc;
    if (vg >= NN) break;
    const float dv = dinv[vg];
    const unsigned us = h2u[((size_t)vg << 6) + lane];
    const float sx = aggf[(vloc << 7) + lane] + bf16lo_to_f32(us);
    const float sy = aggf[(vloc << 7) + 64 + lane] + bf16hi_to_f32(us);
    const float t0 = fmaxf(fmaf(dv, sx, bcv.x), 0.f);
    const float t1 = fmaxf(fmaf(dv, sy, bcv.y), 0.f);

    float p[OUTF];
#pragma unroll
    for (int q = 0; q < OUTF; ++q) p[q] = t0 * wa[q] + t1 * wb[q];

    // halving tree reduce over 128 channels -> 16 outputs spread on lane bits 5..2
    float q8[8];
    const bool u5 = lane & 32;
#pragma unroll
    for (int i = 0; i < 8; ++i) {
      const float send = u5 ? p[i] : p[i + 8];
      const float keep = u5 ? p[i + 8] : p[i];
      q8[i] = keep + __shfl_xor(send, 32);
    }
    float q4[4];
    const bool u4 = lane & 16;
#pragma unroll
    for (int i = 0; i < 4; ++i) {
      const float send = u4 ? q8[i] : q8[i + 4];
      const float keep = u4 ? q8[i + 4] : q8[i];
      q4[i] = keep + __shfl_xor(send, 16);
    }
    float q2[2];
    const bool u3 = lane & 8;
#pragma unroll
    for (int i = 0; i < 2; ++i) {
      const float send = u3 ? q4[i] : q4[i + 2];
      const float keep = u3 ? q4[i + 2] : q4[i];
      q2[i] = keep + __shfl_xor(send, 8);
    }
    const bool u2 = lane & 4;
    const float send = u2 ? q2[0] : q2[1];
    const float keep = u2 ? q2[1] : q2[0];
    float t = keep + __shfl_xor(send, 4);
    t += __shfl_xor(t, 2);
    t += __shfl_xor(t, 1);

    const int o = (lane >> 2) & 15;
    const float lg = t + blv;
    float m = lg;
    m = fmaxf(m, __shfl_xor(m, 4));
    m = fmaxf(m, __shfl_xor(m, 8));
    m = fmaxf(m, __shfl_xor(m, 16));
    m = fmaxf(m, __shfl_xor(m, 32));
    float se = expf(lg - m);
    se += __shfl_xor(se, 4);
    se += __shfl_xor(se, 8);
    se += __shfl_xor(se, 16);
    se += __shfl_xor(se, 32);
    if ((lane & 3) == 0) out[(size_t)vg * OUTF + o] = lg - m - logf(se);
  }
}

// ---------------------------------------------------------------- launch
extern "C" void kernel_launch(void* const* d_in, const int* in_sizes, int n_in,
                              void* d_out, int out_size, void* d_ws, size_t ws_size,
                              hipStream_t stream) {
  const float* x  = (const float*)d_in[0];
  const int*   ei = (const int*)d_in[1];
  const float* Wc = (const float*)d_in[2];
  const float* bc = (const float*)d_in[3];
  const float* Wl = (const float*)d_in[4];
  const float* bl = (const float*)d_in[5];
  float* out = (float*)d_out;

  unsigned short* h2b = (unsigned short*)d_ws;            // 25.6 MB
  unsigned short* WTs = h2b + (size_t)NN * HID;           // 64 KB
  float* dinv   = (float*)(WTs + (size_t)INF_ * HID);     // 400 KB
  int*   deg    = (int*)(dinv + NN);                      // 400 KB
  int*   bcnt   = deg + NN;                               // NBUK
  int*   boff   = bcnt + NBUK;                            // NBUK+1
  int*   cur    = boff + NBUK + 1;                        // NBUK
  unsigned int* binned = (unsigned int*)(cur + NBUK);     // NE = 6.4 MB

  const int* srcv = ei;
  const int* dstv = ei + NE;

  hipMemsetAsync(deg, 0, (size_t)NN * sizeof(int), stream);

  k_deg<<<2048, 256, 0, stream>>>(dstv, deg);
  k_dinv<<<(NN + 255) / 256, 256, 0, stream>>>(deg, dinv);
  k_wprep<<<(INF_ * HID + 255) / 256, 256, 0, stream>>>(Wc, WTs);
  k_gemm<<<(NN + 127) / 128, 256, 0, stream>>>(x, WTs, dinv, h2b);
  k_bucketsum<<<NBUK, 64, 0, stream>>>(deg, bcnt);
  k_bscan<<<1, 256, 0, stream>>>(bcnt, boff, cur);
  k_binfill<<<2048, 256, 0, stream>>>(srcv, dstv, cur, binned);
  k_aggfin<<<NBUK, 256, 0, stream>>>(binned, boff, h2b, dinv, bc, Wl, bl, out);
}

// Round 5
// 344.620 us; speedup vs baseline: 4.5700x; 4.5700x over previous
//
#include <hip/hip_runtime.h>
#include <math.h>

#define NN    100000
#define INF_  256
#define HID   128
#define OUTF  16
#define NE    1600000
#define BUK   256
#define NBUK  ((NN + BUK - 1) / BUK)      // 391
#define BHIST_BLOCKS 64
#define EPH   (NE / BHIST_BLOCKS)         // 25000
#define BIN_BLOCKS 32
#define EPB   (NE / BIN_BLOCKS)           // 50000
#define ROUND_E 2048
#define CAP   32

typedef __attribute__((ext_vector_type(4))) float f32x4;
typedef __attribute__((ext_vector_type(8))) short bf16x8;

__device__ inline unsigned short f32_to_bf16(float f) {
  union { float f; unsigned int u; } v; v.f = f;
  unsigned int x = v.u;
  unsigned int r = x + 0x7fffu + ((x >> 16) & 1u);  // RNE
  return (unsigned short)(r >> 16);
}
__device__ inline float bf16lo_to_f32(unsigned int u) {
  union { unsigned int u; float f; } v; v.u = u << 16; return v.f;
}
__device__ inline float bf16hi_to_f32(unsigned int u) {
  union { unsigned int u; float f; } v; v.u = u & 0xffff0000u; return v.f;
}

// ---------------------------------------------------------------- bucket histogram (LDS-aggregated)
__global__ __launch_bounds__(256) void k_bhist(const int* __restrict__ dst,
                                               int* __restrict__ bcnt) {
  __shared__ int lh[NBUK];
  const int t = threadIdx.x;
  for (int i = t; i < NBUK; i += 256) lh[i] = 0;
  __syncthreads();
  const int beg = blockIdx.x * EPH, end = beg + EPH;
  for (int i = beg + t; i < end; i += 256) atomicAdd(&lh[dst[i] >> 8], 1);
  __syncthreads();
  for (int i = t; i < NBUK; i += 256) {
    const int c = lh[i];
    if (c) atomicAdd(&bcnt[i], c);
  }
}

// ---------------------------------------------------------------- exclusive scan of bucket counts
__global__ __launch_bounds__(256) void k_bscan(const int* __restrict__ bcnt,
                                               int* __restrict__ boff,
                                               int* __restrict__ cur) {
  __shared__ int sh[256];
  const int t = threadIdx.x;
  int v[2];
  int s = 0;
#pragma unroll
  for (int j = 0; j < 2; ++j) {
    const int idx = t * 2 + j;
    v[j] = (idx < NBUK) ? bcnt[idx] : 0;
    s += v[j];
  }
  sh[t] = s;
  __syncthreads();
  for (int off = 1; off < 256; off <<= 1) {
    int tmp = (t >= off) ? sh[t - off] : 0;
    __syncthreads();
    sh[t] += tmp;
    __syncthreads();
  }
  int run = (t > 0) ? sh[t - 1] : 0;
#pragma unroll
  for (int j = 0; j < 2; ++j) {
    const int idx = t * 2 + j;
    if (idx < NBUK) { boff[idx] = run; cur[idx] = run; }
    run += v[j];
  }
  if (t == 255) boff[NBUK] = run;  // == NE
}

// ---------------------------------------------------------------- staged binning: word = src<<8 | (dst&255)
__global__ __launch_bounds__(256) void k_binfill(const int* __restrict__ src,
                                                 const int* __restrict__ dst,
                                                 int* __restrict__ cur,
                                                 unsigned int* __restrict__ binned) {
  __shared__ int scnt[NBUK];
  __shared__ unsigned stg[NBUK * CAP];  // 50 KB
  const int t = threadIdx.x;
  for (int i = t; i < NBUK; i += 256) scnt[i] = 0;
  __syncthreads();
  const int beg = blockIdx.x * EPB, end = beg + EPB;
  for (int rbase = beg; rbase < end; rbase += ROUND_E) {
    // edge phase: up to 8 edges/thread, coalesced
#pragma unroll
    for (int q = 0; q < 8; ++q) {
      const int i = rbase + q * 256 + t;
      if (i < end) {
        const int d = dst[i];
        const int b = d >> 8;
        const unsigned w = ((unsigned)src[i] << 8) | (unsigned)(d & 255);
        const int pos = atomicAdd(&scnt[b], 1);
        if (pos < CAP) stg[b * CAP + pos] = w;
        else binned[atomicAdd(&cur[b], 1)] = w;  // rare overflow fallback
      }
    }
    __syncthreads();
    // flush phase: full 16-word (64B) groups
    for (int b = t; b < NBUK; b += 256) {
      int c = scnt[b]; if (c > CAP) c = CAP;
      const int f = c & ~15;
      if (f) {
        const int base = atomicAdd(&cur[b], f);
        for (int q = 0; q < f; ++q) binned[base + q] = stg[b * CAP + q];
        for (int q = 0; q < c - f; ++q) stg[b * CAP + q] = stg[b * CAP + f + q];
      }
      scnt[b] = c - f;
    }
    __syncthreads();
  }
  // drain remainders
  for (int b = t; b < NBUK; b += 256) {
    int c = scnt[b]; if (c > CAP) c = CAP;
    if (c) {
      const int base = atomicAdd(&cur[b], c);
      for (int q = 0; q < c; ++q) binned[base + q] = stg[b * CAP + q];
    }
  }
}

// ---------------------------------------------------------------- per-bucket: hist -> rowptr/dinv, then csr scatter (L2-local)
__global__ __launch_bounds__(256) void k_csr(const unsigned int* __restrict__ binned,
                                             const int* __restrict__ boff,
                                             int* __restrict__ rowptr,
                                             float* __restrict__ dinv,
                                             int* __restrict__ csr) {
  __shared__ int hist[BUK];
  __shared__ int sh[256];
  __shared__ int lcur[BUK];
  const int b = blockIdx.x, t = threadIdx.x;
  hist[t] = 0;
  __syncthreads();
  const int e0 = boff[b], e1 = boff[b + 1];
  for (int i = e0 + t; i < e1; i += 256) atomicAdd(&hist[binned[i] & 255u], 1);
  __syncthreads();
  const int hv = hist[t];
  sh[t] = hv;
  __syncthreads();
  for (int off = 1; off < 256; off <<= 1) {
    int tmp = (t >= off) ? sh[t - off] : 0;
    __syncthreads();
    sh[t] += tmp;
    __syncthreads();
  }
  const int excl = sh[t] - hv;
  lcur[t] = excl;
  const int nid = b * BUK + t;
  if (nid < NN) {
    rowptr[nid] = e0 + excl;
    dinv[nid] = rsqrtf((float)(hv + 1));
  }
  if (b == NBUK - 1 && t == 0) rowptr[NN] = e1;  // == NE
  __syncthreads();
  for (int i = e0 + t; i < e1; i += 256) {
    const unsigned w = binned[i];
    const int pos = atomicAdd(&lcur[w & 255u], 1);
    csr[e0 + pos] = (int)(w >> 8);
  }
}

// ---------------------------------------------------------------- W prep (bf16, transposed, pre-swizzled 16B chunks)
__global__ __launch_bounds__(256) void k_wprep(const float* __restrict__ W,
                                               unsigned short* __restrict__ WTs) {
  const int i = blockIdx.x * 256 + threadIdx.x;
  if (i >= INF_ * HID) return;
  const int k = i >> 7, n = i & 127;
  const int s = k >> 5, c = (k >> 3) & 3, j = k & 7;
  const int chunk = s * 512 + n * 4 + (c ^ (n & 3));
  WTs[chunk * 8 + j] = f32_to_bf16(W[i]);
}

// ---------------------------------------------------------------- MFMA GEMM: h2b = bf16( (x @ Wc) * dinv[row] )
__global__ __launch_bounds__(256) void k_gemm(const float* __restrict__ x,
                                              const unsigned short* __restrict__ WTs,
                                              const float* __restrict__ dinv,
                                              unsigned short* __restrict__ h2b) {
  __shared__ unsigned short xs[128 * 32];
  __shared__ unsigned short ws[128 * 32];
  const int tid = threadIdx.x;
  const int wave = tid >> 6, lane = tid & 63;
  const int l15 = lane & 15, l4 = lane >> 4;
  const int row0 = blockIdx.x * 128;

  f32x4 acc[2][8];
#pragma unroll
  for (int rb = 0; rb < 2; ++rb)
#pragma unroll
    for (int n = 0; n < 8; ++n) { acc[rb][n].x = 0.f; acc[rb][n].y = 0.f; acc[rb][n].z = 0.f; acc[rb][n].w = 0.f; }

  for (int s = 0; s < 8; ++s) {
#pragma unroll
    for (int p = 0; p < 2; ++p) {
      const int c = tid + p * 256;
      const int row = c >> 2, kc = c & 3;
      const int grow = row0 + row;
      unsigned short tmp[8];
      if (grow < NN) {
        const float4 v0 = *(const float4*)&x[(size_t)grow * INF_ + s * 32 + kc * 8];
        const float4 v1 = *(const float4*)&x[(size_t)grow * INF_ + s * 32 + kc * 8 + 4];
        tmp[0] = f32_to_bf16(v0.x); tmp[1] = f32_to_bf16(v0.y);
        tmp[2] = f32_to_bf16(v0.z); tmp[3] = f32_to_bf16(v0.w);
        tmp[4] = f32_to_bf16(v1.x); tmp[5] = f32_to_bf16(v1.y);
        tmp[6] = f32_to_bf16(v1.z); tmp[7] = f32_to_bf16(v1.w);
      } else {
#pragma unroll
        for (int j = 0; j < 8; ++j) tmp[j] = 0;
      }
      const int phys = kc ^ (row & 3);
      *(bf16x8*)&xs[(row * 4 + phys) * 8] = *(bf16x8*)tmp;
    }
#pragma unroll
    for (int p = 0; p < 2; ++p) {
      const int c = tid + p * 256;
      *(bf16x8*)&ws[c * 8] = *(const bf16x8*)&WTs[(s * 512 + c) * 8];
    }
    __syncthreads();
    bf16x8 af[2];
#pragma unroll
    for (int rb = 0; rb < 2; ++rb) {
      const int row = wave * 32 + rb * 16 + l15;
      af[rb] = *(const bf16x8*)&xs[(row * 4 + (l4 ^ (row & 3))) * 8];
    }
#pragma unroll
    for (int n = 0; n < 8; ++n) {
      const int col = n * 16 + l15;
      const bf16x8 bf = *(const bf16x8*)&ws[(col * 4 + (l4 ^ (col & 3))) * 8];
      acc[0][n] = __builtin_amdgcn_mfma_f32_16x16x32_bf16(af[0], bf, acc[0][n], 0, 0, 0);
      acc[1][n] = __builtin_amdgcn_mfma_f32_16x16x32_bf16(af[1], bf, acc[1][n], 0, 0, 0);
    }
    __syncthreads();
  }
#pragma unroll
  for (int rb = 0; rb < 2; ++rb) {
#pragma unroll
    for (int r = 0; r < 4; ++r) {
      const int rowg = row0 + wave * 32 + rb * 16 + l4 * 4 + r;
      if (rowg < NN) {
        const float dv = dinv[rowg];
#pragma unroll
        for (int n = 0; n < 8; ++n)
          h2b[(size_t)rowg * HID + n * 16 + l15] = f32_to_bf16(acc[rb][n][r] * dv);
      }
    }
  }
}

// ---------------------------------------------------------------- gather + finalize fused (unroll-16 MLP)
__global__ __launch_bounds__(256) void k_gather(const int* __restrict__ rowptr,
                                                const int* __restrict__ csr,
                                                const unsigned short* __restrict__ h2b,
                                                const float* __restrict__ dinv,
                                                const float* __restrict__ bc,
                                                const float* __restrict__ Wl,
                                                const float* __restrict__ bl,
                                                float* __restrict__ out) {
  const int wid = blockIdx.x * 4 + (threadIdx.x >> 6);
  const int lane = threadIdx.x & 63;
  if (wid >= NN) return;
  const int v  = __builtin_amdgcn_readfirstlane(wid);
  const int rp = __builtin_amdgcn_readfirstlane(rowptr[v]);
  const int re = __builtin_amdgcn_readfirstlane(rowptr[v + 1]);
  const unsigned* h2u = (const unsigned*)h2b;  // row v at h2u + (v<<6), lane's dword at +lane

  float ax[8], ay[8];
#pragma unroll
  for (int q = 0; q < 8; ++q) { ax[q] = 0.f; ay[q] = 0.f; }

  int j = rp;
  for (; j + 16 <= re; j += 16) {
    unsigned u[16];
#pragma unroll
    for (int q = 0; q < 16; ++q) u[q] = h2u[((size_t)csr[j + q] << 6) + lane];
#pragma unroll
    for (int q = 0; q < 16; ++q) { ax[q & 7] += bf16lo_to_f32(u[q]); ay[q & 7] += bf16hi_to_f32(u[q]); }
  }
  for (; j + 4 <= re; j += 4) {
    unsigned u[4];
#pragma unroll
    for (int q = 0; q < 4; ++q) u[q] = h2u[((size_t)csr[j + q] << 6) + lane];
#pragma unroll
    for (int q = 0; q < 4; ++q) { ax[q] += bf16lo_to_f32(u[q]); ay[q] += bf16hi_to_f32(u[q]); }
  }
  for (; j < re; ++j) {
    const unsigned u = h2u[((size_t)csr[j] << 6) + lane];
    ax[0] += bf16lo_to_f32(u); ay[0] += bf16hi_to_f32(u);
  }
  const float sx = ((ax[0] + ax[1]) + (ax[2] + ax[3])) + ((ax[4] + ax[5]) + (ax[6] + ax[7]));
  const float sy = ((ay[0] + ay[1]) + (ay[2] + ay[3])) + ((ay[4] + ay[5]) + (ay[6] + ay[7]));

  const int c0 = lane * 2;
  const float dv = dinv[v];
  const unsigned us = h2u[((size_t)v << 6) + lane];
  const float2 bcv = *(const float2*)&bc[c0];
  const float t0 = fmaxf(fmaf(dv, sx + bf16lo_to_f32(us), bcv.x), 0.f);
  const float t1 = fmaxf(fmaf(dv, sy + bf16hi_to_f32(us), bcv.y), 0.f);

  float p[OUTF];
  {
    const float4* wa = (const float4*)&Wl[(size_t)c0 * OUTF];
    const float4* wb = (const float4*)&Wl[(size_t)(c0 + 1) * OUTF];
#pragma unroll
    for (int q = 0; q < 4; ++q) {
      const float4 a = wa[q], b = wb[q];
      p[q * 4 + 0] = t0 * a.x + t1 * b.x;
      p[q * 4 + 1] = t0 * a.y + t1 * b.y;
      p[q * 4 + 2] = t0 * a.z + t1 * b.z;
      p[q * 4 + 3] = t0 * a.w + t1 * b.w;
    }
  }
  // halving tree: outputs end up spread over lane bits 5..2
  const bool u5 = lane & 32;
  float q8[8];
#pragma unroll
  for (int i = 0; i < 8; ++i) {
    const float send = u5 ? p[i] : p[i + 8];
    const float keep = u5 ? p[i + 8] : p[i];
    q8[i] = keep + __shfl_xor(send, 32);
  }
  const bool u4 = lane & 16;
  float q4[4];
#pragma unroll
  for (int i = 0; i < 4; ++i) {
    const float send = u4 ? q8[i] : q8[i + 4];
    const float keep = u4 ? q8[i + 4] : q8[i];
    q4[i] = keep + __shfl_xor(send, 16);
  }
  const bool u3 = lane & 8;
  float q2[2];
#pragma unroll
  for (int i = 0; i < 2; ++i) {
    const float send = u3 ? q4[i] : q4[i + 2];
    const float keep = u3 ? q4[i + 2] : q4[i];
    q2[i] = keep + __shfl_xor(send, 8);
  }
  const bool u2 = lane & 4;
  {
    const float send = u2 ? q2[0] : q2[1];
    const float keep = u2 ? q2[1] : q2[0];
    float t = keep + __shfl_xor(send, 4);
    t += __shfl_xor(t, 2);
    t += __shfl_xor(t, 1);
    const int o = (lane >> 2) & 15;
    const float lg = t + bl[o];
    float m = lg;
    m = fmaxf(m, __shfl_xor(m, 4));
    m = fmaxf(m, __shfl_xor(m, 8));
    m = fmaxf(m, __shfl_xor(m, 16));
    m = fmaxf(m, __shfl_xor(m, 32));
    float se = expf(lg - m);
    se += __shfl_xor(se, 4);
    se += __shfl_xor(se, 8);
    se += __shfl_xor(se, 16);
    se += __shfl_xor(se, 32);
    if ((lane & 3) == 0) out[(size_t)v * OUTF + o] = lg - m - logf(se);
  }
}

// ---------------------------------------------------------------- launch
extern "C" void kernel_launch(void* const* d_in, const int* in_sizes, int n_in,
                              void* d_out, int out_size, void* d_ws, size_t ws_size,
                              hipStream_t stream) {
  const float* x  = (const float*)d_in[0];
  const int*   ei = (const int*)d_in[1];
  const float* Wc = (const float*)d_in[2];
  const float* bc = (const float*)d_in[3];
  const float* Wl = (const float*)d_in[4];
  const float* bl = (const float*)d_in[5];
  float* out = (float*)d_out;

  unsigned short* h2b = (unsigned short*)d_ws;            // 25.6 MB
  unsigned short* WTs = h2b + (size_t)NN * HID;           // 64 KB
  float* dinv   = (float*)(WTs + (size_t)INF_ * HID);     // NN f32
  int*   rowptr = (int*)(dinv + NN);                      // NN+1
  int*   bcnt   = rowptr + NN + 1;                        // NBUK
  int*   boff   = bcnt + NBUK;                            // NBUK+1
  int*   cur    = boff + NBUK + 1;                        // NBUK
  unsigned int* binned = (unsigned int*)(cur + NBUK);     // NE
  int*   csr    = (int*)(binned + NE);                    // NE

  const int* srcv = ei;
  const int* dstv = ei + NE;

  hipMemsetAsync(bcnt, 0, (size_t)NBUK * sizeof(int), stream);

  k_bhist<<<BHIST_BLOCKS, 256, 0, stream>>>(dstv, bcnt);
  k_bscan<<<1, 256, 0, stream>>>(bcnt, boff, cur);
  k_binfill<<<BIN_BLOCKS, 256, 0, stream>>>(srcv, dstv, cur, binned);
  k_csr<<<NBUK, 256, 0, stream>>>(binned, boff, rowptr, dinv, csr);
  k_wprep<<<(INF_ * HID + 255) / 256, 256, 0, stream>>>(Wc, WTs);
  k_gemm<<<(NN + 127) / 128, 256, 0, stream>>>(x, WTs, dinv, h2b);
  k_gather<<<(NN + 3) / 4, 256, 0, stream>>>(rowptr, csr, h2b, dinv, bc, Wl, bl, out);
}

// Round 6
// 323.988 us; speedup vs baseline: 4.8610x; 1.0637x over previous
//
#include <hip/hip_runtime.h>
#include <math.h>

#define NN    100000
#define INF_  256
#define HID   128
#define OUTF  16
#define NE    1600000
#define BUK   256
#define NBUK  ((NN + BUK - 1) / BUK)      // 391
#define NBP   393                         // padded LDS stride (odd -> conflict-free)
#define BHIST_BLOCKS 256
#define EPH   (NE / BHIST_BLOCKS)         // 6250
#define BIN_BLOCKS 512
#define EPB   ((NE + BIN_BLOCKS - 1) / BIN_BLOCKS)  // 3125
#define ROUND_E 2048
#define CAP   16

typedef __attribute__((ext_vector_type(4))) float f32x4;
typedef __attribute__((ext_vector_type(8))) short bf16x8;

__device__ inline unsigned short f32_to_bf16(float f) {
  union { float f; unsigned int u; } v; v.f = f;
  unsigned int x = v.u;
  unsigned int r = x + 0x7fffu + ((x >> 16) & 1u);  // RNE
  return (unsigned short)(r >> 16);
}
__device__ inline float bf16lo_to_f32(unsigned int u) {
  union { unsigned int u; float f; } v; v.u = u << 16; return v.f;
}
__device__ inline float bf16hi_to_f32(unsigned int u) {
  union { unsigned int u; float f; } v; v.u = u & 0xffff0000u; return v.f;
}

// ---------------------------------------------------------------- bucket histogram (LDS-aggregated)
__global__ __launch_bounds__(256) void k_bhist(const int* __restrict__ dst,
                                               int* __restrict__ bcnt) {
  __shared__ int lh[NBUK];
  const int t = threadIdx.x;
  for (int i = t; i < NBUK; i += 256) lh[i] = 0;
  __syncthreads();
  const int beg = blockIdx.x * EPH, end = beg + EPH;
  for (int i = beg + t; i < end; i += 256) atomicAdd(&lh[dst[i] >> 8], 1);
  __syncthreads();
  for (int i = t; i < NBUK; i += 256) {
    const int c = lh[i];
    if (c) atomicAdd(&bcnt[i], c);
  }
}

// ---------------------------------------------------------------- exclusive scan of bucket counts
__global__ __launch_bounds__(256) void k_bscan(const int* __restrict__ bcnt,
                                               int* __restrict__ boff,
                                               int* __restrict__ cur) {
  __shared__ int sh[256];
  const int t = threadIdx.x;
  int v[2];
  int s = 0;
#pragma unroll
  for (int j = 0; j < 2; ++j) {
    const int idx = t * 2 + j;
    v[j] = (idx < NBUK) ? bcnt[idx] : 0;
    s += v[j];
  }
  sh[t] = s;
  __syncthreads();
  for (int off = 1; off < 256; off <<= 1) {
    int tmp = (t >= off) ? sh[t - off] : 0;
    __syncthreads();
    sh[t] += tmp;
    __syncthreads();
  }
  int run = (t > 0) ? sh[t - 1] : 0;
#pragma unroll
  for (int j = 0; j < 2; ++j) {
    const int idx = t * 2 + j;
    if (idx < NBUK) { boff[idx] = run; cur[idx] = run; }
    run += v[j];
  }
  if (t == 255) boff[NBUK] = run;  // == NE
}

// ---------------------------------------------------------------- staged binning: word = src<<8 | (dst&255)
// transposed staging stg[pos*NBP + b]; cooperative 16-lane flush per bucket
__global__ __launch_bounds__(256) void k_binfill(const int* __restrict__ src,
                                                 const int* __restrict__ dst,
                                                 int* __restrict__ cur,
                                                 unsigned int* __restrict__ binned) {
  __shared__ int scnt[NBUK];
  __shared__ unsigned stg[CAP * NBP];  // 16*393*4 = 25.2 KB
  const int t = threadIdx.x;
  const int g = t >> 4, l16 = t & 15;  // 16 groups of 16 lanes
  for (int i = t; i < NBUK; i += 256) scnt[i] = 0;
  __syncthreads();
  const int beg = blockIdx.x * EPB;
  const int end = min(beg + EPB, NE);
  for (int rbase = beg; rbase < end; rbase += ROUND_E) {
    const int rend = min(rbase + ROUND_E, end);
    // edge phase: coalesced reads, LDS staging
#pragma unroll
    for (int q = 0; q < ROUND_E / 256; ++q) {
      const int i = rbase + q * 256 + t;
      if (i < rend) {
        const int d = dst[i];
        const int b = d >> 8;
        const unsigned w = ((unsigned)src[i] << 8) | (unsigned)(d & 255);
        const int pos = atomicAdd(&scnt[b], 1);
        if (pos < CAP) stg[pos * NBP + b] = w;
        else binned[atomicAdd(&cur[b], 1)] = w;  // rare overflow fallback
      }
    }
    __syncthreads();
    // cooperative flush of full 16-word (64B) lines
    for (int b = g; b < NBUK; b += 16) {
      int c = scnt[b]; if (c > CAP) c = CAP;
      if (c >= 16) {
        int base0 = 0;
        if (l16 == 0) base0 = atomicAdd(&cur[b], 16);
        const int base = __shfl(base0, (g & 3) << 4);
        binned[base + l16] = stg[l16 * NBP + b];
        if (l16 == 0) scnt[b] = 0;
      }
    }
    __syncthreads();
  }
  // drain remainders (masked cooperative writes)
  for (int b = g; b < NBUK; b += 16) {
    int c = scnt[b]; if (c > CAP) c = CAP;
    if (c > 0) {
      int base0 = 0;
      if (l16 == 0) base0 = atomicAdd(&cur[b], c);
      const int base = __shfl(base0, (g & 3) << 4);
      if (l16 < c) binned[base + l16] = stg[l16 * NBP + b];
    }
  }
}

// ---------------------------------------------------------------- per-bucket: hist -> rowptr/dinv, then csr scatter (L2-local)
__global__ __launch_bounds__(256) void k_csr(const unsigned int* __restrict__ binned,
                                             const int* __restrict__ boff,
                                             int* __restrict__ rowptr,
                                             float* __restrict__ dinv,
                                             int* __restrict__ csr) {
  __shared__ int hist[BUK];
  __shared__ int sh[256];
  __shared__ int lcur[BUK];
  const int b = blockIdx.x, t = threadIdx.x;
  hist[t] = 0;
  __syncthreads();
  const int e0 = boff[b], e1 = boff[b + 1];
  for (int i = e0 + t; i < e1; i += 256) atomicAdd(&hist[binned[i] & 255u], 1);
  __syncthreads();
  const int hv = hist[t];
  sh[t] = hv;
  __syncthreads();
  for (int off = 1; off < 256; off <<= 1) {
    int tmp = (t >= off) ? sh[t - off] : 0;
    __syncthreads();
    sh[t] += tmp;
    __syncthreads();
  }
  const int excl = sh[t] - hv;
  lcur[t] = excl;
  const int nid = b * BUK + t;
  if (nid < NN) {
    rowptr[nid] = e0 + excl;
    dinv[nid] = rsqrtf((float)(hv + 1));
  }
  if (b == NBUK - 1 && t == 0) rowptr[NN] = e1;  // == NE
  __syncthreads();
  for (int i = e0 + t; i < e1; i += 256) {
    const unsigned w = binned[i];
    const int pos = atomicAdd(&lcur[w & 255u], 1);
    csr[e0 + pos] = (int)(w >> 8);
  }
}

// ---------------------------------------------------------------- W prep (bf16, transposed, pre-swizzled 16B chunks)
__global__ __launch_bounds__(256) void k_wprep(const float* __restrict__ W,
                                               unsigned short* __restrict__ WTs) {
  const int i = blockIdx.x * 256 + threadIdx.x;
  if (i >= INF_ * HID) return;
  const int k = i >> 7, n = i & 127;
  const int s = k >> 5, c = (k >> 3) & 3, j = k & 7;
  const int chunk = s * 512 + n * 4 + (c ^ (n & 3));
  WTs[chunk * 8 + j] = f32_to_bf16(W[i]);
}

// ---------------------------------------------------------------- MFMA GEMM: h2b = bf16( (x @ Wc) * dinv[row] )
__global__ __launch_bounds__(256) void k_gemm(const float* __restrict__ x,
                                              const unsigned short* __restrict__ WTs,
                                              const float* __restrict__ dinv,
                                              unsigned short* __restrict__ h2b) {
  __shared__ unsigned short xs[128 * 32];
  __shared__ unsigned short ws[128 * 32];
  const int tid = threadIdx.x;
  const int wave = tid >> 6, lane = tid & 63;
  const int l15 = lane & 15, l4 = lane >> 4;
  const int row0 = blockIdx.x * 128;

  f32x4 acc[2][8];
#pragma unroll
  for (int rb = 0; rb < 2; ++rb)
#pragma unroll
    for (int n = 0; n < 8; ++n) { acc[rb][n].x = 0.f; acc[rb][n].y = 0.f; acc[rb][n].z = 0.f; acc[rb][n].w = 0.f; }

  for (int s = 0; s < 8; ++s) {
#pragma unroll
    for (int p = 0; p < 2; ++p) {
      const int c = tid + p * 256;
      const int row = c >> 2, kc = c & 3;
      const int grow = row0 + row;
      unsigned short tmp[8];
      if (grow < NN) {
        const float4 v0 = *(const float4*)&x[(size_t)grow * INF_ + s * 32 + kc * 8];
        const float4 v1 = *(const float4*)&x[(size_t)grow * INF_ + s * 32 + kc * 8 + 4];
        tmp[0] = f32_to_bf16(v0.x); tmp[1] = f32_to_bf16(v0.y);
        tmp[2] = f32_to_bf16(v0.z); tmp[3] = f32_to_bf16(v0.w);
        tmp[4] = f32_to_bf16(v1.x); tmp[5] = f32_to_bf16(v1.y);
        tmp[6] = f32_to_bf16(v1.z); tmp[7] = f32_to_bf16(v1.w);
      } else {
#pragma unroll
        for (int j = 0; j < 8; ++j) tmp[j] = 0;
      }
      const int phys = kc ^ (row & 3);
      *(bf16x8*)&xs[(row * 4 + phys) * 8] = *(bf16x8*)tmp;
    }
#pragma unroll
    for (int p = 0; p < 2; ++p) {
      const int c = tid + p * 256;
      *(bf16x8*)&ws[c * 8] = *(const bf16x8*)&WTs[(s * 512 + c) * 8];
    }
    __syncthreads();
    bf16x8 af[2];
#pragma unroll
    for (int rb = 0; rb < 2; ++rb) {
      const int row = wave * 32 + rb * 16 + l15;
      af[rb] = *(const bf16x8*)&xs[(row * 4 + (l4 ^ (row & 3))) * 8];
    }
#pragma unroll
    for (int n = 0; n < 8; ++n) {
      const int col = n * 16 + l15;
      const bf16x8 bf = *(const bf16x8*)&ws[(col * 4 + (l4 ^ (col & 3))) * 8];
      acc[0][n] = __builtin_amdgcn_mfma_f32_16x16x32_bf16(af[0], bf, acc[0][n], 0, 0, 0);
      acc[1][n] = __builtin_amdgcn_mfma_f32_16x16x32_bf16(af[1], bf, acc[1][n], 0, 0, 0);
    }
    __syncthreads();
  }
#pragma unroll
  for (int rb = 0; rb < 2; ++rb) {
#pragma unroll
    for (int r = 0; r < 4; ++r) {
      const int rowg = row0 + wave * 32 + rb * 16 + l4 * 4 + r;
      if (rowg < NN) {
        const float dv = dinv[rowg];
#pragma unroll
        for (int n = 0; n < 8; ++n)
          h2b[(size_t)rowg * HID + n * 16 + l15] = f32_to_bf16(acc[rb][n][r] * dv);
      }
    }
  }
}

// ---------------------------------------------------------------- gather + finalize fused (unroll-16 MLP)
__global__ __launch_bounds__(256) void k_gather(const int* __restrict__ rowptr,
                                                const int* __restrict__ csr,
                                                const unsigned short* __restrict__ h2b,
                                                const float* __restrict__ dinv,
                                                const float* __restrict__ bc,
                                                const float* __restrict__ Wl,
                                                const float* __restrict__ bl,
                                                float* __restrict__ out) {
  const int wid = blockIdx.x * 4 + (threadIdx.x >> 6);
  const int lane = threadIdx.x & 63;
  if (wid >= NN) return;
  const int v  = __builtin_amdgcn_readfirstlane(wid);
  const int rp = __builtin_amdgcn_readfirstlane(rowptr[v]);
  const int re = __builtin_amdgcn_readfirstlane(rowptr[v + 1]);
  const unsigned* h2u = (const unsigned*)h2b;  // row v at h2u + (v<<6), lane's dword at +lane

  float ax[8], ay[8];
#pragma unroll
  for (int q = 0; q < 8; ++q) { ax[q] = 0.f; ay[q] = 0.f; }

  int j = rp;
  for (; j + 16 <= re; j += 16) {
    unsigned u[16];
#pragma unroll
    for (int q = 0; q < 16; ++q) u[q] = h2u[((size_t)csr[j + q] << 6) + lane];
#pragma unroll
    for (int q = 0; q < 16; ++q) { ax[q & 7] += bf16lo_to_f32(u[q]); ay[q & 7] += bf16hi_to_f32(u[q]); }
  }
  for (; j + 4 <= re; j += 4) {
    unsigned u[4];
#pragma unroll
    for (int q = 0; q < 4; ++q) u[q] = h2u[((size_t)csr[j + q] << 6) + lane];
#pragma unroll
    for (int q = 0; q < 4; ++q) { ax[q] += bf16lo_to_f32(u[q]); ay[q] += bf16hi_to_f32(u[q]); }
  }
  for (; j < re; ++j) {
    const unsigned u = h2u[((size_t)csr[j] << 6) + lane];
    ax[0] += bf16lo_to_f32(u); ay[0] += bf16hi_to_f32(u);
  }
  const float sx = ((ax[0] + ax[1]) + (ax[2] + ax[3])) + ((ax[4] + ax[5]) + (ax[6] + ax[7]));
  const float sy = ((ay[0] + ay[1]) + (ay[2] + ay[3])) + ((ay[4] + ay[5]) + (ay[6] + ay[7]));

  const int c0 = lane * 2;
  const float dv = dinv[v];
  const unsigned us = h2u[((size_t)v << 6) + lane];
  const float2 bcv = *(const float2*)&bc[c0];
  const float t0 = fmaxf(fmaf(dv, sx + bf16lo_to_f32(us), bcv.x), 0.f);
  const float t1 = fmaxf(fmaf(dv, sy + bf16hi_to_f32(us), bcv.y), 0.f);

  float p[OUTF];
  {
    const float4* wa = (const float4*)&Wl[(size_t)c0 * OUTF];
    const float4* wb = (const float4*)&Wl[(size_t)(c0 + 1) * OUTF];
#pragma unroll
    for (int q = 0; q < 4; ++q) {
      const float4 a = wa[q], b = wb[q];
      p[q * 4 + 0] = t0 * a.x + t1 * b.x;
      p[q * 4 + 1] = t0 * a.y + t1 * b.y;
      p[q * 4 + 2] = t0 * a.z + t1 * b.z;
      p[q * 4 + 3] = t0 * a.w + t1 * b.w;
    }
  }
  // halving tree: outputs end up spread over lane bits 5..2
  const bool u5 = lane & 32;
  float q8[8];
#pragma unroll
  for (int i = 0; i < 8; ++i) {
    const float send = u5 ? p[i] : p[i + 8];
    const float keep = u5 ? p[i + 8] : p[i];
    q8[i] = keep + __shfl_xor(send, 32);
  }
  const bool u4 = lane & 16;
  float q4[4];
#pragma unroll
  for (int i = 0; i < 4; ++i) {
    const float send = u4 ? q8[i] : q8[i + 4];
    const float keep = u4 ? q8[i + 4] : q8[i];
    q4[i] = keep + __shfl_xor(send, 16);
  }
  const bool u3 = lane & 8;
  float q2[2];
#pragma unroll
  for (int i = 0; i < 2; ++i) {
    const float send = u3 ? q4[i] : q4[i + 2];
    const float keep = u3 ? q4[i + 2] : q4[i];
    q2[i] = keep + __shfl_xor(send, 8);
  }
  const bool u2 = lane & 4;
  {
    const float send = u2 ? q2[0] : q2[1];
    const float keep = u2 ? q2[1] : q2[0];
    float t = keep + __shfl_xor(send, 4);
    t += __shfl_xor(t, 2);
    t += __shfl_xor(t, 1);
    const int o = (lane >> 2) & 15;
    const float lg = t + bl[o];
    float m = lg;
    m = fmaxf(m, __shfl_xor(m, 4));
    m = fmaxf(m, __shfl_xor(m, 8));
    m = fmaxf(m, __shfl_xor(m, 16));
    m = fmaxf(m, __shfl_xor(m, 32));
    float se = expf(lg - m);
    se += __shfl_xor(se, 4);
    se += __shfl_xor(se, 8);
    se += __shfl_xor(se, 16);
    se += __shfl_xor(se, 32);
    if ((lane & 3) == 0) out[(size_t)v * OUTF + o] = lg - m - logf(se);
  }
}

// ---------------------------------------------------------------- launch
extern "C" void kernel_launch(void* const* d_in, const int* in_sizes, int n_in,
                              void* d_out, int out_size, void* d_ws, size_t ws_size,
                              hipStream_t stream) {
  const float* x  = (const float*)d_in[0];
  const int*   ei = (const int*)d_in[1];
  const float* Wc = (const float*)d_in[2];
  const float* bc = (const float*)d_in[3];
  const float* Wl = (const float*)d_in[4];
  const float* bl = (const float*)d_in[5];
  float* out = (float*)d_out;

  unsigned short* h2b = (unsigned short*)d_ws;            // 25.6 MB
  unsigned short* WTs = h2b + (size_t)NN * HID;           // 64 KB
  float* dinv   = (float*)(WTs + (size_t)INF_ * HID);     // NN f32
  int*   rowptr = (int*)(dinv + NN);                      // NN+1
  int*   bcnt   = rowptr + NN + 1;                        // NBUK
  int*   boff   = bcnt + NBUK;                            // NBUK+1
  int*   cur    = boff + NBUK + 1;                        // NBUK
  unsigned int* binned = (unsigned int*)(cur + NBUK);     // NE
  int*   csr    = (int*)(binned + NE);                    // NE

  const int* srcv = ei;
  const int* dstv = ei + NE;

  hipMemsetAsync(bcnt, 0, (size_t)NBUK * sizeof(int), stream);

  k_bhist<<<BHIST_BLOCKS, 256, 0, stream>>>(dstv, bcnt);
  k_bscan<<<1, 256, 0, stream>>>(bcnt, boff, cur);
  k_binfill<<<BIN_BLOCKS, 256, 0, stream>>>(srcv, dstv, cur, binned);
  k_csr<<<NBUK, 256, 0, stream>>>(binned, boff, rowptr, dinv, csr);
  k_wprep<<<(INF_ * HID + 255) / 256, 256, 0, stream>>>(Wc, WTs);
  k_gemm<<<(NN + 127) / 128, 256, 0, stream>>>(x, WTs, dinv, h2b);
  k_gather<<<(NN + 3) / 4, 256, 0, stream>>>(rowptr, csr, h2b, dinv, bc, Wl, bl, out);
}

// Round 7
// 258.827 us; speedup vs baseline: 6.0848x; 1.2518x over previous
//
#include <hip/hip_runtime.h>
#include <math.h>

#define NN    100000
#define INF_  256
#define HID   128
#define OUTF  16
#define NE    1600000
#define BUK   256
#define NBUK  ((NN + BUK - 1) / BUK)      // 391
#define NB_F  128                          // fill blocks
#define EPB_F (NE / NB_F)                  // 12500
#define NB2   (NBUK * NB_F)                // 50048
#define SCAN_T 1024
#define SVPT  ((NB2 + SCAN_T - 1) / SCAN_T)  // 49

typedef __attribute__((ext_vector_type(4))) float f32x4;
typedef __attribute__((ext_vector_type(8))) short bf16x8;

__device__ inline unsigned short f32_to_bf16(float f) {
  union { float f; unsigned int u; } v; v.f = f;
  unsigned int x = v.u;
  unsigned int r = x + 0x7fffu + ((x >> 16) & 1u);  // RNE
  return (unsigned short)(r >> 16);
}
__device__ inline float bf16lo_to_f32(unsigned int u) {
  union { unsigned int u; float f; } v; v.u = u << 16; return v.f;
}
__device__ inline float bf16hi_to_f32(unsigned int u) {
  union { unsigned int u; float f; } v; v.u = u & 0xffff0000u; return v.f;
}

// ---------------------------------------------------------------- per-block bucket histogram -> H[bucket][block]
__global__ __launch_bounds__(256) void k_hist2d(const int* __restrict__ dst,
                                                int* __restrict__ H) {
  __shared__ int lh[NBUK];
  const int t = threadIdx.x;
  for (int i = t; i < NBUK; i += 256) lh[i] = 0;
  __syncthreads();
  const int beg = blockIdx.x * EPB_F;
  for (int i = beg + t; i < beg + EPB_F; i += 256) atomicAdd(&lh[dst[i] >> 8], 1);
  __syncthreads();
  for (int i = t; i < NBUK; i += 256) H[i * NB_F + blockIdx.x] = lh[i];
}

// ---------------------------------------------------------------- single-block exclusive scan of H -> base (NB2+1)
__global__ __launch_bounds__(SCAN_T) void k_scan(const int* __restrict__ H,
                                                 int* __restrict__ base) {
  __shared__ int sh[SCAN_T];
  const int t = threadIdx.x;
  int v[SVPT];
  int s = 0;
#pragma unroll
  for (int j = 0; j < SVPT; ++j) {
    const int idx = t * SVPT + j;
    v[j] = (idx < NB2) ? H[idx] : 0;
    s += v[j];
  }
  sh[t] = s;
  __syncthreads();
  for (int off = 1; off < SCAN_T; off <<= 1) {
    int tmp = (t >= off) ? sh[t - off] : 0;
    __syncthreads();
    sh[t] += tmp;
    __syncthreads();
  }
  int run = (t > 0) ? sh[t - 1] : 0;
#pragma unroll
  for (int j = 0; j < SVPT; ++j) {
    const int idx = t * SVPT + j;
    if (idx < NB2) base[idx] = run;
    run += v[j];
  }
  if (t == SCAN_T - 1) base[NB2] = run;  // == NE
}

// ---------------------------------------------------------------- direct fill: block-owned ranges, no global atomics
// word = src<<8 | (dst&255), grouped by (bucket, block)
__global__ __launch_bounds__(256) void k_fillb(const int* __restrict__ src,
                                               const int* __restrict__ dst,
                                               const int* __restrict__ base,
                                               unsigned int* __restrict__ binned) {
  __shared__ int lbase[NBUK];
  __shared__ int lcnt[NBUK];
  const int t = threadIdx.x;
  for (int i = t; i < NBUK; i += 256) {
    lbase[i] = base[i * NB_F + blockIdx.x];
    lcnt[i] = 0;
  }
  __syncthreads();
  const int beg = blockIdx.x * EPB_F;
#pragma unroll 4
  for (int i = beg + t; i < beg + EPB_F; i += 256) {
    const int d = dst[i];
    const int b = d >> 8;
    const unsigned w = ((unsigned)src[i] << 8) | (unsigned)(d & 255);
    const int pos = atomicAdd(&lcnt[b], 1);
    binned[lbase[b] + pos] = w;
  }
}

// ---------------------------------------------------------------- per-bucket: hist -> rowptr/dinv, then csr scatter (L2-local)
__global__ __launch_bounds__(256) void k_csr(const unsigned int* __restrict__ binned,
                                             const int* __restrict__ base,
                                             int* __restrict__ rowptr,
                                             float* __restrict__ dinv,
                                             int* __restrict__ csr) {
  __shared__ int hist[BUK];
  __shared__ int sh[256];
  __shared__ int lcur[BUK];
  const int b = blockIdx.x, t = threadIdx.x;
  hist[t] = 0;
  __syncthreads();
  const int e0 = base[b * NB_F], e1 = base[(b + 1) * NB_F];
  for (int i = e0 + t; i < e1; i += 256) atomicAdd(&hist[binned[i] & 255u], 1);
  __syncthreads();
  const int hv = hist[t];
  sh[t] = hv;
  __syncthreads();
  for (int off = 1; off < 256; off <<= 1) {
    int tmp = (t >= off) ? sh[t - off] : 0;
    __syncthreads();
    sh[t] += tmp;
    __syncthreads();
  }
  const int excl = sh[t] - hv;
  lcur[t] = excl;
  const int nid = b * BUK + t;
  if (nid < NN) {
    rowptr[nid] = e0 + excl;
    dinv[nid] = rsqrtf((float)(hv + 1));
  }
  if (b == NBUK - 1 && t == 0) rowptr[NN] = e1;  // == NE
  __syncthreads();
  for (int i = e0 + t; i < e1; i += 256) {
    const unsigned w = binned[i];
    const int pos = atomicAdd(&lcur[w & 255u], 1);
    csr[e0 + pos] = (int)(w >> 8);
  }
}

// ---------------------------------------------------------------- W prep (bf16, transposed, pre-swizzled 16B chunks)
__global__ __launch_bounds__(256) void k_wprep(const float* __restrict__ W,
                                               unsigned short* __restrict__ WTs) {
  const int i = blockIdx.x * 256 + threadIdx.x;
  if (i >= INF_ * HID) return;
  const int k = i >> 7, n = i & 127;
  const int s = k >> 5, c = (k >> 3) & 3, j = k & 7;
  const int chunk = s * 512 + n * 4 + (c ^ (n & 3));
  WTs[chunk * 8 + j] = f32_to_bf16(W[i]);
}

// ---------------------------------------------------------------- MFMA GEMM: h2b = bf16( (x @ Wc) * dinv[row] )
__global__ __launch_bounds__(256) void k_gemm(const float* __restrict__ x,
                                              const unsigned short* __restrict__ WTs,
                                              const float* __restrict__ dinv,
                                              unsigned short* __restrict__ h2b) {
  __shared__ unsigned short xs[128 * 32];
  __shared__ unsigned short ws[128 * 32];
  const int tid = threadIdx.x;
  const int wave = tid >> 6, lane = tid & 63;
  const int l15 = lane & 15, l4 = lane >> 4;
  const int row0 = blockIdx.x * 128;

  f32x4 acc[2][8];
#pragma unroll
  for (int rb = 0; rb < 2; ++rb)
#pragma unroll
    for (int n = 0; n < 8; ++n) { acc[rb][n].x = 0.f; acc[rb][n].y = 0.f; acc[rb][n].z = 0.f; acc[rb][n].w = 0.f; }

  for (int s = 0; s < 8; ++s) {
#pragma unroll
    for (int p = 0; p < 2; ++p) {
      const int c = tid + p * 256;
      const int row = c >> 2, kc = c & 3;
      const int grow = row0 + row;
      unsigned short tmp[8];
      if (grow < NN) {
        const float4 v0 = *(const float4*)&x[(size_t)grow * INF_ + s * 32 + kc * 8];
        const float4 v1 = *(const float4*)&x[(size_t)grow * INF_ + s * 32 + kc * 8 + 4];
        tmp[0] = f32_to_bf16(v0.x); tmp[1] = f32_to_bf16(v0.y);
        tmp[2] = f32_to_bf16(v0.z); tmp[3] = f32_to_bf16(v0.w);
        tmp[4] = f32_to_bf16(v1.x); tmp[5] = f32_to_bf16(v1.y);
        tmp[6] = f32_to_bf16(v1.z); tmp[7] = f32_to_bf16(v1.w);
      } else {
#pragma unroll
        for (int j = 0; j < 8; ++j) tmp[j] = 0;
      }
      const int phys = kc ^ (row & 3);
      *(bf16x8*)&xs[(row * 4 + phys) * 8] = *(bf16x8*)tmp;
    }
#pragma unroll
    for (int p = 0; p < 2; ++p) {
      const int c = tid + p * 256;
      *(bf16x8*)&ws[c * 8] = *(const bf16x8*)&WTs[(s * 512 + c) * 8];
    }
    __syncthreads();
    bf16x8 af[2];
#pragma unroll
    for (int rb = 0; rb < 2; ++rb) {
      const int row = wave * 32 + rb * 16 + l15;
      af[rb] = *(const bf16x8*)&xs[(row * 4 + (l4 ^ (row & 3))) * 8];
    }
#pragma unroll
    for (int n = 0; n < 8; ++n) {
      const int col = n * 16 + l15;
      const bf16x8 bf = *(const bf16x8*)&ws[(col * 4 + (l4 ^ (col & 3))) * 8];
      acc[0][n] = __builtin_amdgcn_mfma_f32_16x16x32_bf16(af[0], bf, acc[0][n], 0, 0, 0);
      acc[1][n] = __builtin_amdgcn_mfma_f32_16x16x32_bf16(af[1], bf, acc[1][n], 0, 0, 0);
    }
    __syncthreads();
  }
#pragma unroll
  for (int rb = 0; rb < 2; ++rb) {
#pragma unroll
    for (int r = 0; r < 4; ++r) {
      const int rowg = row0 + wave * 32 + rb * 16 + l4 * 4 + r;
      if (rowg < NN) {
        const float dv = dinv[rowg];
#pragma unroll
        for (int n = 0; n < 8; ++n)
          h2b[(size_t)rowg * HID + n * 16 + l15] = f32_to_bf16(acc[rb][n][r] * dv);
      }
    }
  }
}

// ---------------------------------------------------------------- gather + finalize fused (unroll-16 MLP)
__global__ __launch_bounds__(256) void k_gather(const int* __restrict__ rowptr,
                                                const int* __restrict__ csr,
                                                const unsigned short* __restrict__ h2b,
                                                const float* __restrict__ dinv,
                                                const float* __restrict__ bc,
                                                const float* __restrict__ Wl,
                                                const float* __restrict__ bl,
                                                float* __restrict__ out) {
  const int wid = blockIdx.x * 4 + (threadIdx.x >> 6);
  const int lane = threadIdx.x & 63;
  if (wid >= NN) return;
  const int v  = __builtin_amdgcn_readfirstlane(wid);
  const int rp = __builtin_amdgcn_readfirstlane(rowptr[v]);
  const int re = __builtin_amdgcn_readfirstlane(rowptr[v + 1]);
  const unsigned* h2u = (const unsigned*)h2b;  // row v at h2u + (v<<6), lane's dword at +lane

  float ax[8], ay[8];
#pragma unroll
  for (int q = 0; q < 8; ++q) { ax[q] = 0.f; ay[q] = 0.f; }

  int j = rp;
  for (; j + 16 <= re; j += 16) {
    unsigned u[16];
#pragma unroll
    for (int q = 0; q < 16; ++q) u[q] = h2u[((size_t)csr[j + q] << 6) + lane];
#pragma unroll
    for (int q = 0; q < 16; ++q) { ax[q & 7] += bf16lo_to_f32(u[q]); ay[q & 7] += bf16hi_to_f32(u[q]); }
  }
  for (; j + 4 <= re; j += 4) {
    unsigned u[4];
#pragma unroll
    for (int q = 0; q < 4; ++q) u[q] = h2u[((size_t)csr[j + q] << 6) + lane];
#pragma unroll
    for (int q = 0; q < 4; ++q) { ax[q] += bf16lo_to_f32(u[q]); ay[q] += bf16hi_to_f32(u[q]); }
  }
  for (; j < re; ++j) {
    const unsigned u = h2u[((size_t)csr[j] << 6) + lane];
    ax[0] += bf16lo_to_f32(u); ay[0] += bf16hi_to_f32(u);
  }
  const float sx = ((ax[0] + ax[1]) + (ax[2] + ax[3])) + ((ax[4] + ax[5]) + (ax[6] + ax[7]));
  const float sy = ((ay[0] + ay[1]) + (ay[2] + ay[3])) + ((ay[4] + ay[5]) + (ay[6] + ay[7]));

  const int c0 = lane * 2;
  const float dv = dinv[v];
  const unsigned us = h2u[((size_t)v << 6) + lane];
  const float2 bcv = *(const float2*)&bc[c0];
  const float t0 = fmaxf(fmaf(dv, sx + bf16lo_to_f32(us), bcv.x), 0.f);
  const float t1 = fmaxf(fmaf(dv, sy + bf16hi_to_f32(us), bcv.y), 0.f);

  float p[OUTF];
  {
    const float4* wa = (const float4*)&Wl[(size_t)c0 * OUTF];
    const float4* wb = (const float4*)&Wl[(size_t)(c0 + 1) * OUTF];
#pragma unroll
    for (int q = 0; q < 4; ++q) {
      const float4 a = wa[q], b = wb[q];
      p[q * 4 + 0] = t0 * a.x + t1 * b.x;
      p[q * 4 + 1] = t0 * a.y + t1 * b.y;
      p[q * 4 + 2] = t0 * a.z + t1 * b.z;
      p[q * 4 + 3] = t0 * a.w + t1 * b.w;
    }
  }
  // halving tree: outputs end up spread over lane bits 5..2
  const bool u5 = lane & 32;
  float q8[8];
#pragma unroll
  for (int i = 0; i < 8; ++i) {
    const float send = u5 ? p[i] : p[i + 8];
    const float keep = u5 ? p[i + 8] : p[i];
    q8[i] = keep + __shfl_xor(send, 32);
  }
  const bool u4 = lane & 16;
  float q4[4];
#pragma unroll
  for (int i = 0; i < 4; ++i) {
    const float send = u4 ? q8[i] : q8[i + 4];
    const float keep = u4 ? q8[i + 4] : q8[i];
    q4[i] = keep + __shfl_xor(send, 16);
  }
  const bool u3 = lane & 8;
  float q2[2];
#pragma unroll
  for (int i = 0; i < 2; ++i) {
    const float send = u3 ? q4[i] : q4[i + 2];
    const float keep = u3 ? q4[i + 2] : q4[i];
    q2[i] = keep + __shfl_xor(send, 8);
  }
  const bool u2 = lane & 4;
  {
    const float send = u2 ? q2[0] : q2[1];
    const float keep = u2 ? q2[1] : q2[0];
    float t = keep + __shfl_xor(send, 4);
    t += __shfl_xor(t, 2);
    t += __shfl_xor(t, 1);
    const int o = (lane >> 2) & 15;
    const float lg = t + bl[o];
    float m = lg;
    m = fmaxf(m, __shfl_xor(m, 4));
    m = fmaxf(m, __shfl_xor(m, 8));
    m = fmaxf(m, __shfl_xor(m, 16));
    m = fmaxf(m, __shfl_xor(m, 32));
    float se = expf(lg - m);
    se += __shfl_xor(se, 4);
    se += __shfl_xor(se, 8);
    se += __shfl_xor(se, 16);
    se += __shfl_xor(se, 32);
    if ((lane & 3) == 0) out[(size_t)v * OUTF + o] = lg - m - logf(se);
  }
}

// ---------------------------------------------------------------- launch
extern "C" void kernel_launch(void* const* d_in, const int* in_sizes, int n_in,
                              void* d_out, int out_size, void* d_ws, size_t ws_size,
                              hipStream_t stream) {
  const float* x  = (const float*)d_in[0];
  const int*   ei = (const int*)d_in[1];
  const float* Wc = (const float*)d_in[2];
  const float* bc = (const float*)d_in[3];
  const float* Wl = (const float*)d_in[4];
  const float* bl = (const float*)d_in[5];
  float* out = (float*)d_out;

  unsigned short* h2b = (unsigned short*)d_ws;            // 25.6 MB
  unsigned short* WTs = h2b + (size_t)NN * HID;           // 64 KB
  float* dinv   = (float*)(WTs + (size_t)INF_ * HID);     // NN f32
  int*   rowptr = (int*)(dinv + NN);                      // NN+1
  int*   H      = rowptr + NN + 1;                        // NB2
  int*   base   = H + NB2;                                // NB2+1
  unsigned int* binned = (unsigned int*)(base + NB2 + 1); // NE
  int*   csr    = (int*)(binned + NE);                    // NE

  const int* srcv = ei;
  const int* dstv = ei + NE;

  k_hist2d<<<NB_F, 256, 0, stream>>>(dstv, H);
  k_scan<<<1, SCAN_T, 0, stream>>>(H, base);
  k_fillb<<<NB_F, 256, 0, stream>>>(srcv, dstv, base, binned);
  k_csr<<<NBUK, 256, 0, stream>>>(binned, base, rowptr, dinv, csr);
  k_wprep<<<(INF_ * HID + 255) / 256, 256, 0, stream>>>(Wc, WTs);
  k_gemm<<<(NN + 127) / 128, 256, 0, stream>>>(x, WTs, dinv, h2b);
  k_gather<<<(NN + 3) / 4, 256, 0, stream>>>(rowptr, csr, h2b, dinv, bc, Wl, bl, out);
}